// Round 7
// baseline (33.354 us; speedup 1.0000x reference)
//
#include <hip/hip_runtime.h>
#include <hip/hip_bf16.h>

// Problem constants
#define B_ 4
#define S_ 2048
#define E_ 1024

// K1 tiling (proven in round 6)
#define ES 16                 // e-slices of 64
#define SC 4                  // s-chunks of 512
#define EPS (E_ / ES)         // 64 e's per slice
#define SPC (S_ / SC)         // 512 rows per chunk
#define NPART (ES * SC)       // 64 t-partials per batch

// K2 tiling
#define ISL 8                 // i-slices of 128 columns
#define ICW 128               // columns per i-slice
#define SB 8                  // s-blocks of 256 rows
#define RPB2 (S_ / SB)        // 256 rows per K2 block

// ---------------------------------------------------------------------------
// K1: fused colsum + GEMV1 split-k (unchanged from round 6, minus o-init).
// Block (es, sc, b), 1024 threads:
//   vbs[64] = sum over s-chunk of value[b][s][e-slice]     (LDS reduce)
//   tpart[es*SC+sc][b][j] = sum_{e in slice} vbs[e] * Wv[e][j]  (plain store)
// grid (ES, SC, B_) = 256 blocks, 1024 threads.
// ---------------------------------------------------------------------------
__global__ __launch_bounds__(1024) void k_front(const float* __restrict__ value,
                                                const float* __restrict__ Wv,
                                                float* __restrict__ tpart) {
    const int es = blockIdx.x, sc = blockIdx.y, b = blockIdx.z;
    const int t = threadIdx.x;
    __shared__ float4 red[64][16];
    __shared__ float4 red2[4][16];
    __shared__ float vb[EPS];

    // Phase A: column-sum the value tile [512 s][64 e].
    {
        const int c4 = t & 15, rg = t >> 4;
        const float* base = value + ((size_t)b * S_ + (size_t)sc * SPC) * E_
                            + es * EPS + c4 * 4;
        float4 acc = make_float4(0.f, 0.f, 0.f, 0.f);
#pragma unroll
        for (int r = 0; r < 8; ++r) {
            float4 v = *reinterpret_cast<const float4*>(base + (size_t)(rg + r * 64) * E_);
            acc.x += v.x; acc.y += v.y; acc.z += v.z; acc.w += v.w;
        }
        red[rg][c4] = acc;
    }
    __syncthreads();
    if (t < 64) {
        const int c = t & 15, q = t >> 4;
        float4 s = make_float4(0.f, 0.f, 0.f, 0.f);
#pragma unroll
        for (int k = 0; k < 16; ++k) {
            float4 v = red[q * 16 + k][c];
            s.x += v.x; s.y += v.y; s.z += v.z; s.w += v.w;
        }
        red2[q][c] = s;
    }
    __syncthreads();
    if (t < 16) {
        float4 s0 = red2[0][t], s1 = red2[1][t], s2 = red2[2][t], s3 = red2[3][t];
        float4 s = make_float4(s0.x + s1.x + s2.x + s3.x,
                               s0.y + s1.y + s2.y + s3.y,
                               s0.z + s1.z + s2.z + s3.z,
                               s0.w + s1.w + s2.w + s3.w);
        reinterpret_cast<float4*>(vb)[t] = s;
    }
    __syncthreads();

    // Phase B: t-partial over the 64 Wv rows of this e-slice; j = t.
    {
        const float* wv = Wv + (size_t)(es * EPS) * E_ + t;
        float a = 0.f;
#pragma unroll 8
        for (int k = 0; k < EPS; ++k)
            a = fmaf(vb[k], wv[(size_t)k * E_], a);
        tpart[((size_t)(es * SC + sc) * B_ + b) * E_ + t] = a;
    }
}

// ---------------------------------------------------------------------------
// K2: fused t-reduce + GEMV2-slice + broadcast.
// Block (isl, sb, b), 1024 threads:
//   t_lds[j]  = sum_p tpart[p][b][j] + S*bv[j]           (full t, redundant)
//   o_sl[c]   = sum_j t_lds[j] * Wo[j][isl*128+c] + bo   (128-col slice)
//   out[b][sb*256 .. +256][isl*128 .. +128] = o_sl       (float4 stores)
// grid (ISL, SB, B_) = 256 blocks, 1024 threads.
// ---------------------------------------------------------------------------
__global__ __launch_bounds__(1024) void k_back(const float* __restrict__ tpart,
                                               const float* __restrict__ bv,
                                               const float* __restrict__ Wo,
                                               const float* __restrict__ bo,
                                               float* __restrict__ out) {
    const int isl = blockIdx.x, sb = blockIdx.y, b = blockIdx.z;
    const int t = threadIdx.x;
    __shared__ float t_lds[E_];
    __shared__ float red[8][ICW];
    __shared__ float o_sl[ICW];

    // Reduce tpart over p for j = t (coalesced in j).
    {
        float s = (float)S_ * bv[t];
        const float* tp = tpart + (size_t)b * E_ + t;
#pragma unroll 8
        for (int p = 0; p < NPART; ++p)
            s += tp[(size_t)p * (B_ * E_)];
        t_lds[t] = s;
    }
    __syncthreads();

    // o-slice: split j over 8 groups of 128.
    {
        const int g = t >> 7, cl = t & 127;
        const float* wo = Wo + (size_t)(g * 128) * E_ + isl * ICW + cl;
        float acc = 0.f;
#pragma unroll 8
        for (int jj = 0; jj < 128; ++jj)
            acc = fmaf(t_lds[g * 128 + jj], wo[(size_t)jj * E_], acc);
        red[g][cl] = acc;
    }
    __syncthreads();
    if (t < ICW) {
        float v = bo[isl * ICW + t];
#pragma unroll
        for (int g = 0; g < 8; ++g) v += red[g][t];
        o_sl[t] = v;
    }
    __syncthreads();

    // Broadcast: 256 rows x 128 cols, float4 stores.
    {
        const int c4 = t & 31, rg = t >> 5;      // 32 float4 cols, 32 row groups
        const float4 ov = reinterpret_cast<const float4*>(o_sl)[c4];
        float* base = out + ((size_t)b * S_ + (size_t)sb * RPB2) * E_ + isl * ICW;
#pragma unroll
        for (int k = 0; k < RPB2 / 32; ++k) {
            const int row = rg + k * 32;
            reinterpret_cast<float4*>(base + (size_t)row * E_)[c4] = ov;
        }
    }
}

// ---------------------------------------------------------------------------
extern "C" void kernel_launch(void* const* d_in, const int* in_sizes, int n_in,
                              void* d_out, int out_size, void* d_ws, size_t ws_size,
                              hipStream_t stream) {
    // setup_inputs order: query, key, value, Wq, bq, Wk, bk, Wv, bv, Wo, bo
    const float* value = (const float*)d_in[2];
    const float* Wv    = (const float*)d_in[7];
    const float* bv    = (const float*)d_in[8];
    const float* Wo    = (const float*)d_in[9];
    const float* bo    = (const float*)d_in[10];
    float* out = (float*)d_out;

    float* tpart = (float*)d_ws;                 // [64][B][E]  1 MB

    k_front<<<dim3(ES, SC, B_),  1024, 0, stream>>>(value, Wv, tpart);
    k_back <<<dim3(ISL, SB, B_), 1024, 0, stream>>>(tpart, bv, Wo, bo, out);
}